// Round 4
// baseline (795.159 us; speedup 1.0000x reference)
//
#include <hip/hip_runtime.h>
#include <hip/hip_bf16.h>
#include <math.h>

#define BD   768
#define HH   192
#define NB   8
#define NLQ  64
#define NNC  2048
#define NNE  1200
#define M_ROWS (NB*NNC)   // 16384

typedef float  f32x4  __attribute__((ext_vector_type(4)));
typedef short  bf16x8 __attribute__((ext_vector_type(8)));

__device__ __forceinline__ float wave_sum64(float v){
  #pragma unroll
  for (int off = 32; off; off >>= 1) v += __shfl_xor(v, off);
  return v;
}
__device__ __forceinline__ unsigned short f2bf(float f){
  union { float f; unsigned int u; } v; v.f = f;
  unsigned int u = v.u + 0x7fffu + ((v.u >> 16) & 1u);   // RNE
  return (unsigned short)(u >> 16);
}
__device__ __forceinline__ float bf2f(unsigned short h){
  union { unsigned int u; float f; } v; v.u = ((unsigned int)h) << 16; return v.f;
}
__device__ __forceinline__ unsigned int pack2(float lo, float hi){
  return ((unsigned int)f2bf(hi) << 16) | (unsigned int)f2bf(lo);
}

// ======== coalesced tiled transpose+convert: dst[C][R] = bf16(src[R][C]) ====
__global__ __launch_bounds__(256)
void k_tcvt(const float* __restrict__ src, unsigned short* __restrict__ dst,
            int R, int C){
  __shared__ float T[32][33];
  const int tx = threadIdx.x & 31, ty = threadIdx.x >> 5;   // ty 0..7
  const int c0 = blockIdx.x * 32, r0 = blockIdx.y * 32;
  #pragma unroll
  for (int i = 0; i < 4; ++i)
    T[ty + i * 8][tx] = src[(size_t)(r0 + ty + i * 8) * C + c0 + tx];
  __syncthreads();
  #pragma unroll
  for (int i = 0; i < 4; ++i)
    dst[(size_t)(c0 + ty + i * 8) * R + r0 + tx] = f2bf(T[tx][ty + i * 8]);
}

// ======== A_cat[row] = bf16(concat(ctab[cid], dtab[dst])) ========
__global__ __launch_bounds__(256)
void k_cvt_gather(const int* __restrict__ cids, const int* __restrict__ dsts,
                  const float* __restrict__ ctab, const float* __restrict__ dtab,
                  unsigned short* __restrict__ Acat){
  int idx = blockIdx.x * 256 + threadIdx.x;        // < 16384*192
  int row = idx / 192, kc = (idx - row * 192) * 8;
  int cid = cids[row], dst = dsts[row];
  const float* src = (kc < BD) ? (ctab + (size_t)cid * BD + kc)
                               : (dtab + (size_t)dst * BD + (kc - BD));
  float4 f0 = ((const float4*)src)[0];
  float4 f1 = ((const float4*)src)[1];
  uint4 o;
  o.x = pack2(f0.x, f0.y); o.y = pack2(f0.z, f0.w);
  o.z = pack2(f1.x, f1.y); o.w = pack2(f1.z, f1.w);
  *(uint4*)(Acat + (size_t)row * 1536 + kc) = o;
}

// ======== q_emb (LDS) -> c_query/t_query ; chunk 21 computes mdot ========
__global__ __launch_bounds__(256)
void k_pre(const float* __restrict__ qh,
           const float* __restrict__ W_cs, const float* __restrict__ b_cs,
           const float* __restrict__ W_ts, const float* __restrict__ b_ts,
           const float* __restrict__ w_mem1,
           float* __restrict__ c_query, float* __restrict__ t_query,
           float* __restrict__ mdot){
  const int b = blockIdx.x, chunk = blockIdx.y, t = threadIdx.x;
  if (chunk == 21) {
    if (t < NLQ) {
      const float* q = qh + ((size_t)b * NLQ + t) * BD;
      float acc = 0.f;
      #pragma unroll 4
      for (int d = 0; d < BD; d += 4) {
        float4 v = *(const float4*)(q + d);
        acc += v.x*w_mem1[d] + v.y*w_mem1[d+1] + v.z*w_mem1[d+2] + v.w*w_mem1[d+3];
      }
      mdot[b * NLQ + t] = acc;
    }
    return;
  }
  __shared__ float qe[BD];
  for (int d = t; d < BD; d += 256) {
    const float* p = qh + (size_t)b * NLQ * BD + d;
    float m = -1e30f;
    for (int l = 0; l < NLQ; ++l) m = fmaxf(m, p[(size_t)l * BD]);
    qe[d] = m;
  }
  __syncthreads();
  int j = chunk * 256 + t;
  if (j < 1536) {
    float acc = b_cs[j];
    for (int d = 0; d < BD; ++d) acc += qe[d] * W_cs[(size_t)d * 1536 + j];
    c_query[b * 1536 + j] = acc;
  } else {
    int j2 = j - 1536;
    float acc = b_ts[j2];
    for (int d = 0; d < BD; ++d) acc += qe[d] * W_ts[(size_t)d * 3840 + j2];
    t_query[b * 3840 + j2] = acc;
  }
}

// ======== mem2t[b][h][l] = bf16(qh@W_mem2 + b)  +  qhx conversion ========
// qhx[b][80][768]: rows 0-63 = bf16(qh), row 64 = bf16(w_in1*sqrt(768)), rest 0
__global__ __launch_bounds__(256)
void k_mem2qhx(const float* __restrict__ qh, const float* __restrict__ W_mem2,
               const float* __restrict__ b_mem2, const float* __restrict__ w_in1,
               unsigned short* __restrict__ mem2t, unsigned short* __restrict__ qhx){
  int idx = blockIdx.x * 256 + threadIdx.x;        // < 98304 + 491520
  if (idx < 98304) {
    int l = idx & 63, h = (idx >> 6) % HH, b = idx / 12288;
    const float* q = qh + ((size_t)b * NLQ + l) * BD;
    float acc = b_mem2[h];
    for (int d = 0; d < BD; ++d) acc += q[d] * W_mem2[(size_t)d * HH + h];
    mem2t[((size_t)b * HH + h) * 64 + l] = f2bf(acc);
  } else {
    int i = idx - 98304;
    int b = i / 61440, rk = i - b * 61440;
    int r = rk / BD, k = rk - r * BD;
    unsigned short v;
    if (r < 64)       v = f2bf(qh[((size_t)b * NLQ + r) * BD + k]);
    else if (r == 64) v = f2bf(w_in1[k] * 27.712812921102035f);  // sqrt(768)
    else              v = 0;
    qhx[i] = v;
  }
}

// ======== m97-style bf16 MFMA GEMM, B^T layout ========
template<int BM, int BN, bool BF16OUT>
__global__ __launch_bounds__(256)
void gemm_bt(const unsigned short* __restrict__ A,
             const unsigned short* __restrict__ Bt,
             const float* __restrict__ bias,
             float* __restrict__ Cf, unsigned short* __restrict__ Cb,
             int K, int N)
{
  constexpr int BK = 32;
  __shared__ unsigned short As[BM * BK];
  __shared__ unsigned short Bs[BN * BK];
  const int tid = threadIdx.x;
  const int lane = tid & 63, wave = tid >> 6;
  const int m0 = blockIdx.x * BM, n0 = blockIdx.y * BN;
  const int wm = (wave & 1) * (BM / 2);
  const int wn = (wave >> 1) * (BN / 2);
  constexpr int FM = BM / 32, FN = BN / 32;
  constexpr int CA = (BM * 4) / 256, CB = (BN * 4) / 256;

  f32x4 acc[FM][FN] = {};
  const int fr = lane & 15;
  const int fk = (lane >> 4) * 8;

  for (int k0 = 0; k0 < K; k0 += BK) {
    __syncthreads();
    #pragma unroll
    for (int i = 0; i < CA; ++i) {
      int c = i * 256 + tid;
      const unsigned short* g = A + (size_t)(m0 + (c >> 2)) * K + k0 + (c & 3) * 8;
      __builtin_amdgcn_global_load_lds(
          (const __attribute__((address_space(1))) void*)g,
          (__attribute__((address_space(3))) void*)(As + c * 8), 16, 0, 0);
    }
    #pragma unroll
    for (int i = 0; i < CB; ++i) {
      int c = i * 256 + tid;
      const unsigned short* g = Bt + (size_t)(n0 + (c >> 2)) * K + k0 + (c & 3) * 8;
      __builtin_amdgcn_global_load_lds(
          (const __attribute__((address_space(1))) void*)g,
          (__attribute__((address_space(3))) void*)(Bs + c * 8), 16, 0, 0);
    }
    __syncthreads();
    bf16x8 af[FM], bfv[FN];
    #pragma unroll
    for (int mi = 0; mi < FM; ++mi)
      af[mi] = *(const bf16x8*)(As + (wm + mi * 16 + fr) * BK + fk);
    #pragma unroll
    for (int ni = 0; ni < FN; ++ni)
      bfv[ni] = *(const bf16x8*)(Bs + (wn + ni * 16 + fr) * BK + fk);
    #pragma unroll
    for (int mi = 0; mi < FM; ++mi)
      #pragma unroll
      for (int ni = 0; ni < FN; ++ni)
        acc[mi][ni] = __builtin_amdgcn_mfma_f32_16x16x32_bf16(
            af[mi], bfv[ni], acc[mi][ni], 0, 0, 0);
  }

  const int col16 = lane & 15, row4 = (lane >> 4) * 4;
  #pragma unroll
  for (int mi = 0; mi < FM; ++mi) {
    #pragma unroll
    for (int ni = 0; ni < FN; ++ni) {
      int col = n0 + wn + ni * 16 + col16;
      float bv = bias ? bias[col] : 0.0f;
      int rowb = m0 + wm + mi * 16 + row4;
      #pragma unroll
      for (int r = 0; r < 4; ++r) {
        float v = acc[mi][ni][r] + bv;
        size_t off = (size_t)(rowb + r) * N + col;
        if (BF16OUT) Cb[off] = f2bf(v);
        else         Cf[off] = v;
      }
    }
  }
}

// ======== fused attention v2: register-direct QK^T MFMA, parallel softmax,
//          PV via MFMA (w1 bf16 in LDS x mem2t bf16) ========
__global__ __launch_bounds__(256)
void k_attf(const unsigned short* __restrict__ cf_bf,
            const unsigned short* __restrict__ qhx,
            const float* __restrict__ mdot,
            const unsigned short* __restrict__ mem2t,
            float* __restrict__ out1, float* __restrict__ rowmax)
{
  __shared__ float Sbuf[64][81];
  __shared__ unsigned short w1buf[64][64];
  __shared__ float mds[64];
  const int tid = threadIdx.x, lane = tid & 63, wave = tid >> 6;
  const int m0 = blockIdx.x * 64, b = blockIdx.y;
  if (tid < 64) mds[tid] = mdot[b * NLQ + tid];

  const int fr = lane & 15, fk = (lane >> 4) * 8;
  const unsigned short* Arow = cf_bf + ((size_t)(b * NNC + m0 + wave * 16 + fr)) * BD;
  const unsigned short* Bb = qhx + (size_t)b * 80 * BD;
  f32x4 acc[5] = {};
  #pragma unroll 2
  for (int k0 = 0; k0 < BD; k0 += 32) {
    bf16x8 af = *(const bf16x8*)(Arow + k0 + fk);
    #pragma unroll
    for (int ni = 0; ni < 5; ++ni) {
      bf16x8 bv = *(const bf16x8*)(Bb + (size_t)(ni * 16 + fr) * BD + k0 + fk);
      acc[ni] = __builtin_amdgcn_mfma_f32_16x16x32_bf16(af, bv, acc[ni], 0, 0, 0);
    }
  }
  const int col16 = lane & 15, row4 = (lane >> 4) * 4;
  #pragma unroll
  for (int ni = 0; ni < 5; ++ni)
    #pragma unroll
    for (int r = 0; r < 4; ++r)
      Sbuf[wave * 16 + row4 + r][ni * 16 + col16] = acc[ni][r];
  __syncthreads();

  // softmax: each wave handles its 16 rows; 4 lanes per row, 16 l each
  {
    const float scale = 0.03608439182435161f;    // 1/sqrt(768)
    const int r = wave * 16 + (lane >> 2);
    const int q = lane & 3;
    float e[16];
    float mx = -1e30f;
    #pragma unroll
    for (int i = 0; i < 16; ++i) {
      int l = q * 16 + i;
      float v = mds[l] + Sbuf[r][l] * scale;
      e[i] = v; mx = fmaxf(mx, v);
    }
    mx = fmaxf(mx, __shfl_xor(mx, 1));
    mx = fmaxf(mx, __shfl_xor(mx, 2));
    float s = 0.f;
    #pragma unroll
    for (int i = 0; i < 16; ++i) { e[i] = expf(e[i] - mx); s += e[i]; }
    s += __shfl_xor(s, 1);
    s += __shfl_xor(s, 2);
    float inv = 1.f / s;
    if (q == 0) rowmax[b * NNC + m0 + r] = mx + Sbuf[r][64] * scale;  // + idot
    #pragma unroll
    for (int i = 0; i < 16; ++i) w1buf[r][q * 16 + i] = f2bf(e[i] * inv);
  }
  __syncthreads();

  // PV: out1[64,192] = w1[64,64] @ mem2t[192,64]^T
  f32x4 acc2[12] = {};
  const unsigned short* Mb = mem2t + (size_t)b * HH * 64;
  #pragma unroll
  for (int kk = 0; kk < 2; ++kk) {
    bf16x8 af = *(const bf16x8*)(&w1buf[wave * 16 + fr][kk * 32 + fk]);
    #pragma unroll
    for (int ni = 0; ni < 12; ++ni) {
      bf16x8 bv = *(const bf16x8*)(Mb + (size_t)(ni * 16 + fr) * 64 + kk * 32 + fk);
      acc2[ni] = __builtin_amdgcn_mfma_f32_16x16x32_bf16(af, bv, acc2[ni], 0, 0, 0);
    }
  }
  #pragma unroll
  for (int ni = 0; ni < 12; ++ni)
    #pragma unroll
    for (int r = 0; r < 4; ++r)
      out1[(size_t)(b * NNC + m0 + wave * 16 + row4 + r) * HH + ni * 16 + col16]
          = acc2[ni][r];
}

// ======== w2 softmax over n + out2 = w2^T@inp2, per b ========
__global__ __launch_bounds__(256)
void k_w2out2(const float* __restrict__ rowmax, const float* __restrict__ inp2,
              float* __restrict__ out2)
{
  const int b = blockIdx.x, t = threadIdx.x;
  __shared__ float red[256];
  __shared__ float w2s[NNC];
  const float* rm = rowmax + (size_t)b * NNC;
  float m = -1e30f;
  for (int n = t; n < NNC; n += 256) m = fmaxf(m, rm[n]);
  red[t] = m; __syncthreads();
  for (int s = 128; s; s >>= 1) { if (t < s) red[t] = fmaxf(red[t], red[t+s]); __syncthreads(); }
  m = red[0]; __syncthreads();
  float ssum = 0.f;
  for (int n = t; n < NNC; n += 256) { float e = expf(rm[n] - m); w2s[n] = e; ssum += e; }
  red[t] = ssum; __syncthreads();
  for (int s = 128; s; s >>= 1) { if (t < s) red[t] += red[t+s]; __syncthreads(); }
  float inv = 1.f / red[0];
  __syncthreads();
  if (t < HH) {
    float acc = 0.f;
    const float* ip = inp2 + (size_t)b * NNC * HH + t;
    #pragma unroll 4
    for (int n = 0; n < NNC; ++n) acc += w2s[n] * ip[(size_t)n * HH];
    out2[b * HH + t] = acc * inv;
  }
}

// ======== merged logits: blocks [0,4096) concept, [4096,6496) triple ========
__global__ __launch_bounds__(256)
void k_logits(const unsigned short* __restrict__ cf_bf, const float* __restrict__ inp2,
              const float* __restrict__ out1, const float* __restrict__ out2,
              const float* __restrict__ c_query, const float* __restrict__ t_query,
              const int* __restrict__ head_idxs, const int* __restrict__ tail_idxs,
              const int* __restrict__ rel_ids, const float* __restrict__ rtab,
              float* __restrict__ out)
{
  __shared__ float tqs[3840];
  const int blk = blockIdx.x, lane = threadIdx.x & 63, w = threadIdx.x >> 6;
  if (blk < 4096) {
    const int bn = blk * 4 + w;
    const int b = bn >> 11, n = bn & 2047;
    const float* cq  = c_query + (size_t)b * 1536;
    const unsigned short* cfr = cf_bf + (size_t)bn * BD;
    const float* i2  = inp2 + (size_t)bn * HH;
    const float* o1  = out1 + (size_t)bn * HH;
    const float* o2  = out2 + (size_t)b * HH;
    float acc = 0.f;
    for (int d = lane; d < BD; d += 64) acc += bf2f(cfr[d]) * cq[d];
    #pragma unroll
    for (int j = 0; j < 3; ++j) {
      int h = lane + 64 * j;
      float a = i2[h], o = o1[h];
      acc += a * cq[768+h] + o * cq[960+h] + a*o * cq[1152+h] + o2[h]*o * cq[1344+h];
    }
    acc = wave_sum64(acc);
    if (lane == 0) out[(size_t)b * 3248 + n] = 1.f / (1.f + expf(-acc));
  } else {
    const int blk2 = blk - 4096;
    const int b = blk2 / 300;
    const int e = (blk2 % 300) * 4 + w;
    const float* tq = t_query + (size_t)b * 3840;
    for (int i = threadIdx.x; i < 3840; i += 256) tqs[i] = tq[i];
    __syncthreads();
    const int be = b * NNE + e;
    const int hi = head_idxs[be], ti = tail_idxs[be], rid = rel_ids[be];
    const unsigned short* ch = cf_bf + ((size_t)b * NNC + hi) * BD;
    const unsigned short* ct = cf_bf + ((size_t)b * NNC + ti) * BD;
    const float* rr = rtab + (size_t)rid * BD;
    const float* i2 = inp2 + ((size_t)b * NNC + hi) * HH;
    const float* o1 = out1 + ((size_t)b * NNC + hi) * HH;
    const float* o2 = out2 + (size_t)b * HH;
    float acc = 0.f;
    for (int d = lane; d < BD; d += 64) {
      float hd = bf2f(ch[d]), td = bf2f(ct[d]);
      acc += hd * tqs[d] + rr[d] * tqs[768+d] + td * tqs[1536+d] + hd*td * tqs[2304+d];
    }
    #pragma unroll
    for (int j = 0; j < 3; ++j) {
      int h = lane + 64 * j;
      float a = i2[h], o = o1[h];
      acc += a * tqs[3072+h] + o * tqs[3264+h] + a*o * tqs[3456+h] + o2[h]*o * tqs[3648+h];
    }
    acc = wave_sum64(acc);
    if (lane == 0) out[(size_t)b * 3248 + 2048 + e] = 1.f / (1.f + expf(-acc));
  }
}

extern "C" void kernel_launch(void* const* d_in, const int* in_sizes, int n_in,
                              void* d_out, int out_size, void* d_ws, size_t ws_size,
                              hipStream_t stream) {
  const float* qh        = (const float*)d_in[0];
  const int*   head_cids = (const int*)d_in[2];
  const int*   distances = (const int*)d_in[3];
  const int*   head_idxs = (const int*)d_in[4];
  const int*   tail_idxs = (const int*)d_in[5];
  const int*   rel_ids   = (const int*)d_in[6];
  const float* ctab      = (const float*)d_in[7];
  const float* dtab      = (const float*)d_in[8];
  const float* rtab      = (const float*)d_in[9];
  const float* W_ce      = (const float*)d_in[10];
  const float* b_ce      = (const float*)d_in[11];
  const float* W_cs      = (const float*)d_in[12];
  const float* b_cs      = (const float*)d_in[13];
  const float* W_ts      = (const float*)d_in[14];
  const float* b_ts      = (const float*)d_in[15];
  const float* w_in1     = (const float*)d_in[16];
  const float* w_mem1    = (const float*)d_in[17];
  const float* W_in2     = (const float*)d_in[18];
  const float* b_in2     = (const float*)d_in[19];
  const float* W_mem2    = (const float*)d_in[20];
  const float* b_mem2    = (const float*)d_in[21];
  float* out = (float*)d_out;

  // ---- workspace layout (~105 MB) ----
  float* fp      = (float*)d_ws;
  float* c_query = fp;                    fp += 12288;
  float* t_query = fp;                    fp += 30720;
  float* mdot    = fp;                    fp += 512;
  float* rowmax  = fp;                    fp += 16384;
  float* out2    = fp;                    fp += 1536;
  float* inp2    = fp;                    fp += 3145728;
  float* out1    = fp;                    fp += 3145728;
  unsigned short* cf_bf  = (unsigned short*)fp;
  unsigned short* Wce_t  = cf_bf  + 12582912ull;    // 768*1536
  unsigned short* Win2_t = Wce_t  + 1179648ull;     // 192*768
  unsigned short* qhx    = Win2_t + 147456ull;      // 8*80*768
  unsigned short* mem2t  = qhx    + 491520ull;      // 8*192*64
  unsigned short* A_cat  = mem2t  + 98304ull;       // 16384*1536

  // ---- conversions / precompute ----
  k_tcvt<<<dim3(BD/32, 1536/32), 256, 0, stream>>>(W_ce, Wce_t, 1536, BD);
  k_tcvt<<<dim3(HH/32, BD/32), 256, 0, stream>>>(W_in2, Win2_t, BD, HH);
  k_cvt_gather<<<(M_ROWS*192)/256, 256, 0, stream>>>(head_cids, distances, ctab, dtab, A_cat);
  k_pre<<<dim3(NB, 22), 256, 0, stream>>>(qh, W_cs, b_cs, W_ts, b_ts, w_mem1,
                                          c_query, t_query, mdot);
  k_mem2qhx<<<(98304 + 491520)/256, 256, 0, stream>>>(qh, W_mem2, b_mem2, w_in1,
                                                      mem2t, qhx);

  // ---- MFMA GEMMs ----
  gemm_bt<128,128,true><<<dim3(M_ROWS/128, BD/128), 256, 0, stream>>>(
      A_cat, Wce_t, b_ce, nullptr, cf_bf, 1536, BD);
  gemm_bt<128,64,false><<<dim3(M_ROWS/128, HH/64), 256, 0, stream>>>(
      cf_bf, Win2_t, b_in2, inp2, nullptr, BD, HH);

  // ---- fused attention ----
  k_attf<<<dim3(NNC/64, NB), 256, 0, stream>>>(cf_bf, qhx, mdot, mem2t, out1, rowmax);

  // ---- w2/out2 + scoring ----
  k_w2out2<<<NB, 256, 0, stream>>>(rowmax, inp2, out2);
  k_logits<<<4096 + 2400, 256, 0, stream>>>(cf_bf, inp2, out1, out2, c_query, t_query,
                                            head_idxs, tail_idxs, rel_ids, rtab, out);
}

// Round 6
// 662.523 us; speedup vs baseline: 1.2002x; 1.2002x over previous
//
#include <hip/hip_runtime.h>
#include <hip/hip_bf16.h>
#include <math.h>

#define BD   768
#define HH   192
#define NB   8
#define NLQ  64
#define NNC  2048
#define NNE  1200
#define M_ROWS (NB*NNC)   // 16384

typedef float  f32x4  __attribute__((ext_vector_type(4)));
typedef short  bf16x8 __attribute__((ext_vector_type(8)));

__device__ __forceinline__ float wave_sum64(float v){
  #pragma unroll
  for (int off = 32; off; off >>= 1) v += __shfl_xor(v, off);
  return v;
}
__device__ __forceinline__ unsigned short f2bf(float f){
  union { float f; unsigned int u; } v; v.f = f;
  unsigned int u = v.u + 0x7fffu + ((v.u >> 16) & 1u);   // RNE
  return (unsigned short)(u >> 16);
}
__device__ __forceinline__ float bf2f(unsigned short h){
  union { unsigned int u; float f; } v; v.u = ((unsigned int)h) << 16; return v.f;
}
__device__ __forceinline__ unsigned int pack2(float lo, float hi){
  return ((unsigned int)f2bf(hi) << 16) | (unsigned int)f2bf(lo);
}

// ======== coalesced tiled transpose+convert: dst[C][R] = bf16(src[R][C]) ====
__global__ __launch_bounds__(256)
void k_tcvt(const float* __restrict__ src, unsigned short* __restrict__ dst,
            int R, int C){
  __shared__ float T[32][33];
  const int tx = threadIdx.x & 31, ty = threadIdx.x >> 5;   // ty 0..7
  const int c0 = blockIdx.x * 32, r0 = blockIdx.y * 32;
  #pragma unroll
  for (int i = 0; i < 4; ++i)
    T[ty + i * 8][tx] = src[(size_t)(r0 + ty + i * 8) * C + c0 + tx];
  __syncthreads();
  #pragma unroll
  for (int i = 0; i < 4; ++i)
    dst[(size_t)(c0 + ty + i * 8) * R + r0 + tx] = f2bf(T[tx][ty + i * 8]);
}

// ======== A_cat[row] = bf16(concat(ctab[cid], dtab[dst])) ========
__global__ __launch_bounds__(256)
void k_cvt_gather(const int* __restrict__ cids, const int* __restrict__ dsts,
                  const float* __restrict__ ctab, const float* __restrict__ dtab,
                  unsigned short* __restrict__ Acat){
  int idx = blockIdx.x * 256 + threadIdx.x;        // < 16384*192
  int row = idx / 192, kc = (idx - row * 192) * 8;
  int cid = cids[row], dst = dsts[row];
  const float* src = (kc < BD) ? (ctab + (size_t)cid * BD + kc)
                               : (dtab + (size_t)dst * BD + (kc - BD));
  float4 f0 = ((const float4*)src)[0];
  float4 f1 = ((const float4*)src)[1];
  uint4 o;
  o.x = pack2(f0.x, f0.y); o.y = pack2(f0.z, f0.w);
  o.z = pack2(f1.x, f1.y); o.w = pack2(f1.z, f1.w);
  *(uint4*)(Acat + (size_t)row * 1536 + kc) = o;
}

// ======== q_emb (LDS) -> c_query/t_query ; chunk 21 computes mdot ========
__global__ __launch_bounds__(256)
void k_pre(const float* __restrict__ qh,
           const float* __restrict__ W_cs, const float* __restrict__ b_cs,
           const float* __restrict__ W_ts, const float* __restrict__ b_ts,
           const float* __restrict__ w_mem1,
           float* __restrict__ c_query, float* __restrict__ t_query,
           float* __restrict__ mdot){
  const int b = blockIdx.x, chunk = blockIdx.y, t = threadIdx.x;
  if (chunk == 21) {
    if (t < NLQ) {
      const float* q = qh + ((size_t)b * NLQ + t) * BD;
      float acc = 0.f;
      #pragma unroll 4
      for (int d = 0; d < BD; d += 4) {
        float4 v = *(const float4*)(q + d);
        acc += v.x*w_mem1[d] + v.y*w_mem1[d+1] + v.z*w_mem1[d+2] + v.w*w_mem1[d+3];
      }
      mdot[b * NLQ + t] = acc;
    }
    return;
  }
  __shared__ float qe[BD];
  for (int d = t; d < BD; d += 256) {
    const float* p = qh + (size_t)b * NLQ * BD + d;
    float m = -1e30f;
    for (int l = 0; l < NLQ; ++l) m = fmaxf(m, p[(size_t)l * BD]);
    qe[d] = m;
  }
  __syncthreads();
  int j = chunk * 256 + t;
  if (j < 1536) {
    float acc = b_cs[j];
    for (int d = 0; d < BD; ++d) acc += qe[d] * W_cs[(size_t)d * 1536 + j];
    c_query[b * 1536 + j] = acc;
  } else {
    int j2 = j - 1536;
    float acc = b_ts[j2];
    for (int d = 0; d < BD; ++d) acc += qe[d] * W_ts[(size_t)d * 3840 + j2];
    t_query[b * 3840 + j2] = acc;
  }
}

// ======== mem2t[b][h][l] = bf16(qh@W_mem2 + b)  +  qhx conversion ========
// Coalesced: adjacent threads share the q row (broadcast) and read W coalesced.
// qhx[b][80][768]: rows 0-63 = bf16(qh), row 64 = bf16(w_in1*sqrt(768)), rest 0
__global__ __launch_bounds__(256)
void k_mem2qhx(const float* __restrict__ qh, const float* __restrict__ W_mem2,
               const float* __restrict__ b_mem2, const float* __restrict__ w_in1,
               unsigned short* __restrict__ mem2t, unsigned short* __restrict__ qhx){
  int idx = blockIdx.x * 256 + threadIdx.x;        // < 98304 + 491520
  if (idx < 98304) {
    int h = idx % HH, bl = idx / HH;               // bl = b*64 + l
    int b = bl >> 6, l = bl & 63;
    const float* q = qh + (size_t)bl * BD;
    float acc = b_mem2[h];
    for (int d = 0; d < BD; ++d) acc += q[d] * W_mem2[(size_t)d * HH + h];
    mem2t[((size_t)b * HH + h) * 64 + l] = f2bf(acc);
  } else {
    int i = idx - 98304;
    int b = i / 61440, rk = i - b * 61440;
    int r = rk / BD, k = rk - r * BD;
    unsigned short v;
    if (r < 64)       v = f2bf(qh[((size_t)b * NLQ + r) * BD + k]);
    else if (r == 64) v = f2bf(w_in1[k] * 27.712812921102035f);  // sqrt(768)
    else              v = 0;
    qhx[i] = v;
  }
}

// ======== m97-style bf16 MFMA GEMM, B^T layout ========
template<int BM, int BN, bool BF16OUT>
__global__ __launch_bounds__(256)
void gemm_bt(const unsigned short* __restrict__ A,
             const unsigned short* __restrict__ Bt,
             const float* __restrict__ bias,
             float* __restrict__ Cf, unsigned short* __restrict__ Cb,
             int K, int N)
{
  constexpr int BK = 32;
  __shared__ unsigned short As[BM * BK];
  __shared__ unsigned short Bs[BN * BK];
  const int tid = threadIdx.x;
  const int lane = tid & 63, wave = tid >> 6;
  const int m0 = blockIdx.x * BM, n0 = blockIdx.y * BN;
  const int wm = (wave & 1) * (BM / 2);
  const int wn = (wave >> 1) * (BN / 2);
  constexpr int FM = BM / 32, FN = BN / 32;
  constexpr int CA = (BM * 4) / 256, CB = (BN * 4) / 256;

  f32x4 acc[FM][FN] = {};
  const int fr = lane & 15;
  const int fk = (lane >> 4) * 8;

  for (int k0 = 0; k0 < K; k0 += BK) {
    __syncthreads();
    #pragma unroll
    for (int i = 0; i < CA; ++i) {
      int c = i * 256 + tid;
      const unsigned short* g = A + (size_t)(m0 + (c >> 2)) * K + k0 + (c & 3) * 8;
      __builtin_amdgcn_global_load_lds(
          (const __attribute__((address_space(1))) void*)g,
          (__attribute__((address_space(3))) void*)(As + c * 8), 16, 0, 0);
    }
    #pragma unroll
    for (int i = 0; i < CB; ++i) {
      int c = i * 256 + tid;
      const unsigned short* g = Bt + (size_t)(n0 + (c >> 2)) * K + k0 + (c & 3) * 8;
      __builtin_amdgcn_global_load_lds(
          (const __attribute__((address_space(1))) void*)g,
          (__attribute__((address_space(3))) void*)(Bs + c * 8), 16, 0, 0);
    }
    __syncthreads();
    bf16x8 af[FM], bfv[FN];
    #pragma unroll
    for (int mi = 0; mi < FM; ++mi)
      af[mi] = *(const bf16x8*)(As + (wm + mi * 16 + fr) * BK + fk);
    #pragma unroll
    for (int ni = 0; ni < FN; ++ni)
      bfv[ni] = *(const bf16x8*)(Bs + (wn + ni * 16 + fr) * BK + fk);
    #pragma unroll
    for (int mi = 0; mi < FM; ++mi)
      #pragma unroll
      for (int ni = 0; ni < FN; ++ni)
        acc[mi][ni] = __builtin_amdgcn_mfma_f32_16x16x32_bf16(
            af[mi], bfv[ni], acc[mi][ni], 0, 0, 0);
  }

  const int col16 = lane & 15, row4 = (lane >> 4) * 4;
  #pragma unroll
  for (int mi = 0; mi < FM; ++mi) {
    #pragma unroll
    for (int ni = 0; ni < FN; ++ni) {
      int col = n0 + wn + ni * 16 + col16;
      float bv = bias ? bias[col] : 0.0f;
      int rowb = m0 + wm + mi * 16 + row4;
      #pragma unroll
      for (int r = 0; r < 4; ++r) {
        float v = acc[mi][ni][r] + bv;
        size_t off = (size_t)(rowb + r) * N + col;
        if (BF16OUT) Cb[off] = f2bf(v);
        else         Cf[off] = v;
      }
    }
  }
}

// ======== fused attention: LDS-staged QK^T MFMA + parallel softmax +
//          PV via MFMA — R4 barrier structure restored ========
__global__ __launch_bounds__(256)
void k_attf(const unsigned short* __restrict__ cf_bf,
            const unsigned short* __restrict__ qhx,
            const float* __restrict__ mdot,
            const unsigned short* __restrict__ mem2t,
            float* __restrict__ out1, float* __restrict__ rowmax)
{
  __shared__ unsigned short As[64 * 32];
  __shared__ unsigned short Bs[80 * 32];
  __shared__ float Sbuf[64][81];
  __shared__ unsigned short w1buf[64][72];   // stride 72: 16B-aligned, spreads banks
  __shared__ float mds[64];
  const int tid = threadIdx.x, lane = tid & 63, wave = tid >> 6;
  const int m0 = blockIdx.x * 64, b = blockIdx.y;
  if (tid < 64) mds[tid] = mdot[b * NLQ + tid];
  const unsigned short* Ab = cf_bf + ((size_t)b * NNC + m0) * BD;
  const unsigned short* Bb = qhx + (size_t)b * 80 * BD;
  const int fr = lane & 15, fk = (lane >> 4) * 8;
  const int wm = wave * 16;
  f32x4 acc[5] = {};

  for (int k0 = 0; k0 < BD; k0 += 32) {
    __syncthreads();
    {
      int c = tid;   // A: 64 rows x 4 chunks = 256
      const unsigned short* g = Ab + (size_t)(c >> 2) * BD + k0 + (c & 3) * 8;
      __builtin_amdgcn_global_load_lds(
          (const __attribute__((address_space(1))) void*)g,
          (__attribute__((address_space(3))) void*)(As + c * 8), 16, 0, 0);
    }
    {
      int c = tid;   // B: 80 rows x 4 chunks = 320
      const unsigned short* g = Bb + (size_t)(c >> 2) * BD + k0 + (c & 3) * 8;
      __builtin_amdgcn_global_load_lds(
          (const __attribute__((address_space(1))) void*)g,
          (__attribute__((address_space(3))) void*)(Bs + c * 8), 16, 0, 0);
      if (tid < 64) {
        c = 256 + tid;
        g = Bb + (size_t)(c >> 2) * BD + k0 + (c & 3) * 8;
        __builtin_amdgcn_global_load_lds(
            (const __attribute__((address_space(1))) void*)g,
            (__attribute__((address_space(3))) void*)(Bs + c * 8), 16, 0, 0);
      }
    }
    __syncthreads();
    bf16x8 af = *(const bf16x8*)(As + (wm + fr) * 32 + fk);
    #pragma unroll
    for (int ni = 0; ni < 5; ++ni) {
      bf16x8 bv = *(const bf16x8*)(Bs + (ni * 16 + fr) * 32 + fk);
      acc[ni] = __builtin_amdgcn_mfma_f32_16x16x32_bf16(af, bv, acc[ni], 0, 0, 0);
    }
  }
  const int col16 = lane & 15, row4 = (lane >> 4) * 4;
  #pragma unroll
  for (int ni = 0; ni < 5; ++ni)
    #pragma unroll
    for (int r = 0; r < 4; ++r)
      Sbuf[wm + row4 + r][ni * 16 + col16] = acc[ni][r];
  __syncthreads();

  // softmax: each wave its own 16 rows; 4 lanes per row, 16 l each
  {
    const float scale = 0.03608439182435161f;    // 1/sqrt(768)
    const int r = wm + (lane >> 2);
    const int q = lane & 3;
    float e[16];
    float mx = -1e30f;
    #pragma unroll
    for (int i = 0; i < 16; ++i) {
      int l = q * 16 + i;
      float v = mds[l] + Sbuf[r][l] * scale;
      e[i] = v; mx = fmaxf(mx, v);
    }
    mx = fmaxf(mx, __shfl_xor(mx, 1));
    mx = fmaxf(mx, __shfl_xor(mx, 2));
    float s = 0.f;
    #pragma unroll
    for (int i = 0; i < 16; ++i) { e[i] = expf(e[i] - mx); s += e[i]; }
    s += __shfl_xor(s, 1);
    s += __shfl_xor(s, 2);
    float inv = 1.f / s;
    if (q == 0) rowmax[b * NNC + m0 + r] = mx + Sbuf[r][64] * scale;  // + idot
    #pragma unroll
    for (int i = 0; i < 16; ++i) w1buf[r][q * 16 + i] = f2bf(e[i] * inv);
  }
  __syncthreads();

  // PV: out1[64,192] = w1[64,64] @ mem2t[192,64]^T
  f32x4 acc2[12] = {};
  const unsigned short* Mb = mem2t + (size_t)b * HH * 64;
  #pragma unroll
  for (int kk = 0; kk < 2; ++kk) {
    bf16x8 af = *(const bf16x8*)(&w1buf[wm + fr][kk * 32 + fk]);
    #pragma unroll
    for (int ni = 0; ni < 12; ++ni) {
      bf16x8 bv = *(const bf16x8*)(Mb + (size_t)(ni * 16 + fr) * 64 + kk * 32 + fk);
      acc2[ni] = __builtin_amdgcn_mfma_f32_16x16x32_bf16(af, bv, acc2[ni], 0, 0, 0);
    }
  }
  #pragma unroll
  for (int ni = 0; ni < 12; ++ni)
    #pragma unroll
    for (int r = 0; r < 4; ++r)
      out1[(size_t)(b * NNC + m0 + wm + row4 + r) * HH + ni * 16 + col16]
          = acc2[ni][r];
}

// ======== w2 softmax over n (normalized weights) ========
__global__ __launch_bounds__(256)
void k_w2(const float* __restrict__ rowmax, float* __restrict__ w2buf)
{
  const int b = blockIdx.x, t = threadIdx.x;
  __shared__ float red[256];
  const float* rm = rowmax + (size_t)b * NNC;
  float m = -1e30f;
  for (int n = t; n < NNC; n += 256) m = fmaxf(m, rm[n]);
  red[t] = m; __syncthreads();
  for (int s = 128; s; s >>= 1) { if (t < s) red[t] = fmaxf(red[t], red[t+s]); __syncthreads(); }
  m = red[0]; __syncthreads();
  float ssum = 0.f;
  for (int n = t; n < NNC; n += 256) { float e = expf(rm[n] - m); w2buf[b*NNC + n] = e; ssum += e; }
  red[t] = ssum; __syncthreads();
  for (int s = 128; s; s >>= 1) { if (t < s) red[t] += red[t+s]; __syncthreads(); }
  float inv = 1.f / red[0];
  for (int n = t; n < NNC; n += 256) w2buf[b*NNC + n] *= inv;
}

// ======== out2 partials ========
__global__ __launch_bounds__(192)
void k_out2p(const float* __restrict__ w2buf, const float* __restrict__ inp2,
             float* __restrict__ part)
{
  const int g = blockIdx.x, b = blockIdx.y, h = threadIdx.x;
  const float* w  = w2buf + (size_t)b * NNC + g * 128;
  const float* ip = inp2 + ((size_t)b * NNC + g * 128) * HH + h;
  float acc = 0.f;
  for (int n = 0; n < 128; ++n) acc += w[n] * ip[(size_t)n * HH];
  part[((size_t)b * 16 + g) * HH + h] = acc;
}
__global__ __launch_bounds__(192)
void k_out2r(const float* __restrict__ part, float* __restrict__ out2)
{
  const int b = blockIdx.x, h = threadIdx.x;
  float acc = 0.f;
  #pragma unroll
  for (int g = 0; g < 16; ++g) acc += part[((size_t)b * 16 + g) * HH + h];
  out2[b * HH + h] = acc;
}

// ======== merged logits: blocks [0,4096) concept, [4096,6496) triple ========
__global__ __launch_bounds__(256)
void k_logits(const unsigned short* __restrict__ cf_bf, const float* __restrict__ inp2,
              const float* __restrict__ out1, const float* __restrict__ out2,
              const float* __restrict__ c_query, const float* __restrict__ t_query,
              const int* __restrict__ head_idxs, const int* __restrict__ tail_idxs,
              const int* __restrict__ rel_ids, const float* __restrict__ rtab,
              float* __restrict__ out)
{
  __shared__ float tqs[3840];
  const int blk = blockIdx.x, lane = threadIdx.x & 63, w = threadIdx.x >> 6;
  if (blk < 4096) {
    const int bn = blk * 4 + w;
    const int b = bn >> 11, n = bn & 2047;
    const float* cq  = c_query + (size_t)b * 1536;
    const unsigned short* cfr = cf_bf + (size_t)bn * BD;
    const float* i2  = inp2 + (size_t)bn * HH;
    const float* o1  = out1 + (size_t)bn * HH;
    const float* o2  = out2 + (size_t)b * HH;
    float acc = 0.f;
    for (int d = lane; d < BD; d += 64) acc += bf2f(cfr[d]) * cq[d];
    #pragma unroll
    for (int j = 0; j < 3; ++j) {
      int h = lane + 64 * j;
      float a = i2[h], o = o1[h];
      acc += a * cq[768+h] + o * cq[960+h] + a*o * cq[1152+h] + o2[h]*o * cq[1344+h];
    }
    acc = wave_sum64(acc);
    if (lane == 0) out[(size_t)b * 3248 + n] = 1.f / (1.f + expf(-acc));
  } else {
    const int blk2 = blk - 4096;
    const int b = blk2 / 300;
    const int e = (blk2 % 300) * 4 + w;
    const float* tq = t_query + (size_t)b * 3840;
    for (int i = threadIdx.x; i < 3840; i += 256) tqs[i] = tq[i];
    __syncthreads();
    const int be = b * NNE + e;
    const int hi = head_idxs[be], ti = tail_idxs[be], rid = rel_ids[be];
    const unsigned short* ch = cf_bf + ((size_t)b * NNC + hi) * BD;
    const unsigned short* ct = cf_bf + ((size_t)b * NNC + ti) * BD;
    const float* rr = rtab + (size_t)rid * BD;
    const float* i2 = inp2 + ((size_t)b * NNC + hi) * HH;
    const float* o1 = out1 + ((size_t)b * NNC + hi) * HH;
    const float* o2 = out2 + (size_t)b * HH;
    float acc = 0.f;
    for (int d = lane; d < BD; d += 64) {
      float hd = bf2f(ch[d]), td = bf2f(ct[d]);
      acc += hd * tqs[d] + rr[d] * tqs[768+d] + td * tqs[1536+d] + hd*td * tqs[2304+d];
    }
    #pragma unroll
    for (int j = 0; j < 3; ++j) {
      int h = lane + 64 * j;
      float a = i2[h], o = o1[h];
      acc += a * tqs[3072+h] + o * tqs[3264+h] + a*o * tqs[3456+h] + o2[h]*o * tqs[3648+h];
    }
    acc = wave_sum64(acc);
    if (lane == 0) out[(size_t)b * 3248 + 2048 + e] = 1.f / (1.f + expf(-acc));
  }
}

extern "C" void kernel_launch(void* const* d_in, const int* in_sizes, int n_in,
                              void* d_out, int out_size, void* d_ws, size_t ws_size,
                              hipStream_t stream) {
  const float* qh        = (const float*)d_in[0];
  const int*   head_cids = (const int*)d_in[2];
  const int*   distances = (const int*)d_in[3];
  const int*   head_idxs = (const int*)d_in[4];
  const int*   tail_idxs = (const int*)d_in[5];
  const int*   rel_ids   = (const int*)d_in[6];
  const float* ctab      = (const float*)d_in[7];
  const float* dtab      = (const float*)d_in[8];
  const float* rtab      = (const float*)d_in[9];
  const float* W_ce      = (const float*)d_in[10];
  const float* b_ce      = (const float*)d_in[11];
  const float* W_cs      = (const float*)d_in[12];
  const float* b_cs      = (const float*)d_in[13];
  const float* W_ts      = (const float*)d_in[14];
  const float* b_ts      = (const float*)d_in[15];
  const float* w_in1     = (const float*)d_in[16];
  const float* w_mem1    = (const float*)d_in[17];
  const float* W_in2     = (const float*)d_in[18];
  const float* b_in2     = (const float*)d_in[19];
  const float* W_mem2    = (const float*)d_in[20];
  const float* b_mem2    = (const float*)d_in[21];
  float* out = (float*)d_out;

  // ---- workspace layout (~105 MB) ----
  float* fp      = (float*)d_ws;
  float* c_query = fp;                    fp += 12288;
  float* t_query = fp;                    fp += 30720;
  float* mdot    = fp;                    fp += 512;
  float* rowmax  = fp;                    fp += 16384;
  float* w2buf   = fp;                    fp += 16384;
  float* part    = fp;                    fp += 24576;
  float* out2    = fp;                    fp += 1536;
  float* inp2    = fp;                    fp += 3145728;
  float* out1    = fp;                    fp += 3145728;
  unsigned short* cf_bf  = (unsigned short*)fp;
  unsigned short* Wce_t  = cf_bf  + 12582912ull;    // 768*1536
  unsigned short* Win2_t = Wce_t  + 1179648ull;     // 192*768
  unsigned short* qhx    = Win2_t + 147456ull;      // 8*80*768
  unsigned short* mem2t  = qhx    + 491520ull;      // 8*192*64
  unsigned short* A_cat  = mem2t  + 98304ull;       // 16384*1536

  // ---- conversions / precompute ----
  k_tcvt<<<dim3(BD/32, 1536/32), 256, 0, stream>>>(W_ce, Wce_t, 1536, BD);
  k_tcvt<<<dim3(HH/32, BD/32), 256, 0, stream>>>(W_in2, Win2_t, BD, HH);
  k_cvt_gather<<<(M_ROWS*192)/256, 256, 0, stream>>>(head_cids, distances, ctab, dtab, A_cat);
  k_pre<<<dim3(NB, 22), 256, 0, stream>>>(qh, W_cs, b_cs, W_ts, b_ts, w_mem1,
                                          c_query, t_query, mdot);
  k_mem2qhx<<<(98304 + 491520)/256, 256, 0, stream>>>(qh, W_mem2, b_mem2, w_in1,
                                                      mem2t, qhx);

  // ---- MFMA GEMMs ----
  gemm_bt<128,128,true><<<dim3(M_ROWS/128, BD/128), 256, 0, stream>>>(
      A_cat, Wce_t, b_ce, nullptr, cf_bf, 1536, BD);
  gemm_bt<128,64,false><<<dim3(M_ROWS/128, HH/64), 256, 0, stream>>>(
      cf_bf, Win2_t, b_in2, inp2, nullptr, BD, HH);

  // ---- fused attention ----
  k_attf<<<dim3(NNC/64, NB), 256, 0, stream>>>(cf_bf, qhx, mdot, mem2t, out1, rowmax);

  // ---- w2 / out2 / scoring ----
  k_w2<<<NB, 256, 0, stream>>>(rowmax, w2buf);
  k_out2p<<<dim3(16, NB), 192, 0, stream>>>(w2buf, inp2, part);
  k_out2r<<<NB, 192, 0, stream>>>(part, out2);
  k_logits<<<4096 + 2400, 256, 0, stream>>>(cf_bf, inp2, out1, out2, c_query, t_query,
                                            head_idxs, tail_idxs, rel_ids, rtab, out);
}